// Round 1
// baseline (2068.540 us; speedup 1.0000x reference)
//
#include <hip/hip_runtime.h>

// GridPooling: dense-key unique + segment mean + fp32 projection.
// Key = ((batch*128 + gx)*128 + gy)*128 + gz, gx=grid_coord_x>>1, etc.
// KEY_SPACE = 4*128^3 = 8388608 (33.5 MB hist, L3-resident).

#define KEY_SPACE (4 * 128 * 128 * 128)
#define SCAN_TPB 256
#define SCAN_ITEMS 16
#define SCAN_BLOCK_KEYS (SCAN_TPB * SCAN_ITEMS)       // 4096
#define SCAN_NBLOCKS (KEY_SPACE / SCAN_BLOCK_KEYS)    // 2048
#define CIN 64
#define COUT 128
#define RPB 32   // rows per matmul block

// ---- fill default outputs (padded-slot semantics of jnp.unique fill_value=-1)
__global__ __launch_bounds__(256) void fill_defaults(
    float* __restrict__ out_coord, float* __restrict__ out_grid,
    float* __restrict__ out_batch, float* __restrict__ out_counts, int n) {
  int i = blockIdx.x * 256 + threadIdx.x;
  if (i >= n) return;
  out_counts[i] = 0.0f;
  out_batch[i] = -1.0f;              // -1 // 128^3 == -1 (floor div)
  out_grid[3 * i + 0] = 127.0f;      // (-1 mod 128^3) decodes to (127,127,127)
  out_grid[3 * i + 1] = 127.0f;
  out_grid[3 * i + 2] = 127.0f;
  out_coord[3 * i + 0] = 0.0f;
  out_coord[3 * i + 1] = 0.0f;
  out_coord[3 * i + 2] = 0.0f;
}

// ---- compute packed keys + histogram
__global__ __launch_bounds__(256) void keys_hist(
    const int* __restrict__ grid_coord, const int* __restrict__ batch,
    int* __restrict__ keys, int* __restrict__ hist, int n) {
  int i = blockIdx.x * 256 + threadIdx.x;
  if (i >= n) return;
  int gx = grid_coord[3 * i + 0] >> 1;
  int gy = grid_coord[3 * i + 1] >> 1;
  int gz = grid_coord[3 * i + 2] >> 1;
  int k = (((batch[i] << 7) | gx) << 7 | gy) << 7 | gz;
  keys[i] = k;
  atomicAdd(&hist[k], 1);
}

// ---- scan pass 1: per-block occupancy counts
__global__ __launch_bounds__(SCAN_TPB) void scan_partials(
    const int* __restrict__ hist, int* __restrict__ partials) {
  __shared__ int sdata[SCAN_TPB];
  int t = threadIdx.x;
  int base = blockIdx.x * SCAN_BLOCK_KEYS + t * SCAN_ITEMS;
  int cnt = 0;
#pragma unroll
  for (int i = 0; i < SCAN_ITEMS; ++i) cnt += (hist[base + i] != 0);
  sdata[t] = cnt;
  __syncthreads();
  for (int s = SCAN_TPB / 2; s > 0; s >>= 1) {
    if (t < s) sdata[t] += sdata[t + s];
    __syncthreads();
  }
  if (t == 0) partials[blockIdx.x] = sdata[0];
}

// ---- scan pass 2: exclusive scan over 2048 partials (single block)
__global__ __launch_bounds__(256) void scan_mid(int* __restrict__ partials) {
  __shared__ int sdata[256];
  int t = threadIdx.x;
  int vals[SCAN_NBLOCKS / 256];
  int s = 0;
#pragma unroll
  for (int i = 0; i < SCAN_NBLOCKS / 256; ++i) {
    vals[i] = partials[t * (SCAN_NBLOCKS / 256) + i];
    s += vals[i];
  }
  sdata[t] = s;
  __syncthreads();
  for (int off = 1; off < 256; off <<= 1) {
    int v = (t >= off) ? sdata[t - off] : 0;
    __syncthreads();
    sdata[t] += v;
    __syncthreads();
  }
  int run = (t > 0) ? sdata[t - 1] : 0;
#pragma unroll
  for (int i = 0; i < SCAN_NBLOCKS / 256; ++i) {
    partials[t * (SCAN_NBLOCKS / 256) + i] = run;
    run += vals[i];
  }
}

// ---- scan pass 3: assign ranks to present keys; emit uniq-derived outputs
__global__ __launch_bounds__(SCAN_TPB) void rank_scatter(
    const int* __restrict__ hist, const int* __restrict__ blockOff,
    int* __restrict__ rank, float* __restrict__ out_counts,
    float* __restrict__ out_batch, float* __restrict__ out_grid) {
  __shared__ int sdata[SCAN_TPB];
  int t = threadIdx.x;
  int base = blockIdx.x * SCAN_BLOCK_KEYS + t * SCAN_ITEMS;
  int hv[SCAN_ITEMS];
  int cnt = 0;
#pragma unroll
  for (int i = 0; i < SCAN_ITEMS; ++i) {
    hv[i] = hist[base + i];
    cnt += (hv[i] != 0);
  }
  sdata[t] = cnt;
  __syncthreads();
  for (int off = 1; off < SCAN_TPB; off <<= 1) {
    int v = (t >= off) ? sdata[t - off] : 0;
    __syncthreads();
    sdata[t] += v;
    __syncthreads();
  }
  int u = blockOff[blockIdx.x] + ((t > 0) ? sdata[t - 1] : 0);
#pragma unroll
  for (int i = 0; i < SCAN_ITEMS; ++i) {
    if (hv[i]) {
      int k = base + i;
      rank[k] = u;
      out_counts[u] = (float)hv[i];
      out_batch[u] = (float)(k >> 21);
      out_grid[3 * u + 0] = (float)((k >> 14) & 127);
      out_grid[3 * u + 1] = (float)((k >> 7) & 127);
      out_grid[3 * u + 2] = (float)(k & 127);
      ++u;
    }
  }
}

// ---- per-point cluster id (inverse index); overwrite keys with rank
__global__ __launch_bounds__(256) void cluster_pass(
    int* __restrict__ keys, const int* __restrict__ rank,
    float* __restrict__ out_cluster, int n) {
  int i = blockIdx.x * 256 + threadIdx.x;
  if (i >= n) return;
  int u = rank[keys[i]];
  keys[i] = u;
  out_cluster[i] = (float)u;
}

// ---- accumulate per-voxel feature sums (64-wide) + coord sums
__global__ __launch_bounds__(256) void accumulate(
    const float* __restrict__ feat, const float* __restrict__ coord,
    const int* __restrict__ cluster, const float* __restrict__ counts_f,
    float* __restrict__ sum_feat, float* __restrict__ out_coord, int n) {
  int gid = blockIdx.x * 256 + threadIdx.x;
  int i = gid >> 6;
  int c = gid & 63;
  if (i >= n) return;
  int u = cluster[i];
  float cnt = counts_f[u];
  float v = feat[(size_t)i * CIN + c];
  if (cnt == 1.0f) {
    sum_feat[(size_t)u * CIN + c] = v;          // singleton voxel: no race
  } else {
    atomicAdd(&sum_feat[(size_t)u * CIN + c], v);
  }
  if (c < 3) {
    float cv = coord[3 * i + c];
    if (cnt == 1.0f) out_coord[3 * u + c] = cv;
    else atomicAdd(&out_coord[3 * u + c], cv);
  }
}

// ---- dense projection over unique rows: out = (sum/cnt) @ W + b ; pad rows -> 0
__global__ __launch_bounds__(256) void matmul(
    const float* __restrict__ sum_feat, const float* __restrict__ counts_f,
    const float* __restrict__ W, const float* __restrict__ b,
    float* __restrict__ out_feat, int n) {
  __shared__ float Wl[CIN * COUT];   // 32 KB
  __shared__ float bl[COUT];
  __shared__ float sl[RPB * CIN];    // 8 KB
  __shared__ float cl[RPB];
  int t = threadIdx.x;
  for (int idx = t; idx < CIN * COUT / 4; idx += 256)
    *(float4*)&Wl[idx * 4] = *(const float4*)&W[idx * 4];
  if (t < COUT) bl[t] = b[t];
  int row0 = blockIdx.x * RPB;
  for (int idx = t; idx < RPB * CIN / 4; idx += 256) {
    size_t off = (size_t)row0 * CIN + (size_t)idx * 4;
    float4 v = make_float4(0.f, 0.f, 0.f, 0.f);
    if (off + 3 < (size_t)n * CIN) v = *(const float4*)&sum_feat[off];
    *(float4*)&sl[idx * 4] = v;
  }
  if (t < RPB) {
    int u = row0 + t;
    cl[t] = (u < n) ? counts_f[u] : 0.0f;
  }
  __syncthreads();

  int g = t >> 5;     // row group 0..7 (4 rows each)
  int jl = t & 31;    // channel quad 0..31 -> channels 4*jl..4*jl+3
  float acc[4][4] = {};
  for (int c = 0; c < CIN; c += 4) {
    float4 w0 = *(const float4*)&Wl[(c + 0) * COUT + 4 * jl];
    float4 w1 = *(const float4*)&Wl[(c + 1) * COUT + 4 * jl];
    float4 w2 = *(const float4*)&Wl[(c + 2) * COUT + 4 * jl];
    float4 w3 = *(const float4*)&Wl[(c + 3) * COUT + 4 * jl];
#pragma unroll
    for (int rr = 0; rr < 4; ++rr) {
      float4 s4 = *(const float4*)&sl[(4 * g + rr) * CIN + c];
      acc[rr][0] += s4.x * w0.x + s4.y * w1.x + s4.z * w2.x + s4.w * w3.x;
      acc[rr][1] += s4.x * w0.y + s4.y * w1.y + s4.z * w2.y + s4.w * w3.y;
      acc[rr][2] += s4.x * w0.z + s4.y * w1.z + s4.z * w2.z + s4.w * w3.z;
      acc[rr][3] += s4.x * w0.w + s4.y * w1.w + s4.z * w2.w + s4.w * w3.w;
    }
  }
#pragma unroll
  for (int rr = 0; rr < 4; ++rr) {
    int u = row0 + 4 * g + rr;
    if (u >= n) continue;
    float cnt = cl[4 * g + rr];
    float4 o;
    if (cnt > 0.0f) {
      o.x = acc[rr][0] / cnt + bl[4 * jl + 0];
      o.y = acc[rr][1] / cnt + bl[4 * jl + 1];
      o.z = acc[rr][2] / cnt + bl[4 * jl + 2];
      o.w = acc[rr][3] / cnt + bl[4 * jl + 3];
    } else {
      o = make_float4(0.f, 0.f, 0.f, 0.f);   // padded unique slots -> 0
    }
    *(float4*)&out_feat[(size_t)u * COUT + 4 * jl] = o;
  }
}

// ---- divide accumulated coords by counts (in place)
__global__ __launch_bounds__(256) void coord_div(
    float* __restrict__ out_coord, const float* __restrict__ counts_f, int n) {
  int gid = blockIdx.x * 256 + threadIdx.x;
  if (gid >= 3 * n) return;
  float c = counts_f[gid / 3];
  if (c > 1.0f) out_coord[gid] /= c;
}

extern "C" void kernel_launch(void* const* d_in, const int* in_sizes, int n_in,
                              void* d_out, int out_size, void* d_ws, size_t ws_size,
                              hipStream_t stream) {
  const float* feat = (const float*)d_in[0];
  const float* coord = (const float*)d_in[1];
  const int* grid_coord = (const int*)d_in[2];
  const int* batch = (const int*)d_in[3];
  const float* W = (const float*)d_in[4];
  const float* b = (const float*)d_in[5];
  int n = in_sizes[3];

  float* out = (float*)d_out;
  float* out_feat = out;                                  // n*128
  float* out_coord = out_feat + (size_t)n * COUT;         // n*3
  float* out_grid = out_coord + (size_t)n * 3;            // n*3
  float* out_batch = out_grid + (size_t)n * 3;            // n
  float* out_cluster = out_batch + n;                     // n
  float* out_counts = out_cluster + n;                    // n

  char* ws = (char*)d_ws;
  int* hist = (int*)ws;                                   // KEY_SPACE
  int* rank = hist + KEY_SPACE;                           // KEY_SPACE
  int* blockOff = rank + KEY_SPACE;                       // SCAN_NBLOCKS
  int* keys = blockOff + SCAN_NBLOCKS;                    // n
  size_t sum_off = ((size_t)(2 * KEY_SPACE + SCAN_NBLOCKS + n) * 4 + 255) & ~(size_t)255;
  float* sum_feat = (float*)(ws + sum_off);               // n*64 floats

  hipMemsetAsync(hist, 0, (size_t)KEY_SPACE * 4, stream);
  hipMemsetAsync(sum_feat, 0, (size_t)n * CIN * 4, stream);

  int nb = (n + 255) / 256;
  fill_defaults<<<nb, 256, 0, stream>>>(out_coord, out_grid, out_batch, out_counts, n);
  keys_hist<<<nb, 256, 0, stream>>>(grid_coord, batch, keys, hist, n);
  scan_partials<<<SCAN_NBLOCKS, SCAN_TPB, 0, stream>>>(hist, blockOff);
  scan_mid<<<1, 256, 0, stream>>>(blockOff);
  rank_scatter<<<SCAN_NBLOCKS, SCAN_TPB, 0, stream>>>(hist, blockOff, rank,
                                                      out_counts, out_batch, out_grid);
  cluster_pass<<<nb, 256, 0, stream>>>(keys, rank, out_cluster, n);
  accumulate<<<(n * 64 + 255) / 256, 256, 0, stream>>>(feat, coord, keys, out_counts,
                                                       sum_feat, out_coord, n);
  matmul<<<(n + RPB - 1) / RPB, 256, 0, stream>>>(sum_feat, out_counts, W, b, out_feat, n);
  coord_div<<<(3 * n + 255) / 256, 256, 0, stream>>>(out_coord, out_counts, n);
}